// Round 19
// baseline (90.224 us; speedup 1.0000x reference)
//
#include <hip/hip_runtime.h>
#include <hip/hip_bf16.h>

#define BB 8
#define SS 4096
#define DD 1024
#define KK 32
#define EE 8
#define PP 4

// ---- output float offsets ----
#define O0 0L
#define O1 262144L
#define O2 524288L
#define O3 1572864L
#define O4 1835008L
#define O5 2097152L
#define O6 3145728L

// ---- workspace float offsets ----
#define WA 0L            // per-chunk sm stats: 128 chunks * 64
#define WB 8192L         // final m / 1/sum per (b,k) (fallback path)
#define WPKH 16384L      // W packed hi: 32768 ushort = 16384 floats
#define WPKL 32768L      // W packed lo
#define PWFH 49152L      // pw frags hi: 1M ushort = 524288 floats
#define PWFL 573440L     // pw frags lo
#define WC2 1097728L     // logits partials (8.4MB) THEN slots partials (16.8MB)

typedef __attribute__((ext_vector_type(8))) short short8v;
typedef __attribute__((ext_vector_type(4))) float f32x4;

__device__ __forceinline__ unsigned short f2bf(float f) {
    unsigned u = __builtin_bit_cast(unsigned, f);
    unsigned r = (u + 0x7FFFu + ((u >> 16) & 1u)) >> 16;
    return (unsigned short)r;
}
__device__ __forceinline__ float bf2f(unsigned short h) {
    return __builtin_bit_cast(float, (unsigned)h << 16);
}

// ============ K0: pack W into B^T-fragment order, bf16 hi+lo ==============
__global__ __launch_bounds__(256) void k_wprep(const float* __restrict__ Wp,
    unsigned short* __restrict__ wh, unsigned short* __restrict__ wl)
{
    const int t  = blockIdx.x * 256 + threadIdx.x;
    const int l  = t & 63;
    const int tt = (t >> 6) & 1;
    const int ks = t >> 7;
    const int col = tt * 16 + (l & 15);
    const int dbase = ks * 32 + (l >> 4) * 8;
    const long obase = ((long)(ks * 2 + tt) * 64 + l) * 8;
#pragma unroll
    for (int j = 0; j < 8; ++j) {
        const float w = Wp[(long)(dbase + j) * KK + col];
        const unsigned short h = f2bf(w);
        const float lo = w - bf2f(h);
        wh[obase + j] = h;
        wl[obase + j] = f2bf(lo);
    }
}

// ============ K1: MFMA logits GEMM (champion: 2 K-halves, grid 1024) =======
__global__ __launch_bounds__(256) void k_logits_mfma(const float* __restrict__ x,
    const unsigned short* __restrict__ wh, const unsigned short* __restrict__ wl,
    float* __restrict__ wsP)
{
    const int tid  = threadIdx.x;
    const int wv   = tid >> 6;
    const int lane = tid & 63;
    const int blk  = blockIdx.x;
    const int tile = blk >> 1, half = blk & 1;
    const long tokw = (long)tile * 64 + wv * 16;
    const int mrow = lane & 15;
    const int kg   = lane >> 4;

    const float* xr = x + (tokw + mrow) * DD + half * 512 + kg * 8;
    const uint4* bh = reinterpret_cast<const uint4*>(wh) + (long)half * 16 * 2 * 64 + lane;
    const uint4* bl = reinterpret_cast<const uint4*>(wl) + (long)half * 16 * 2 * 64 + lane;

    f32x4 acc0 = {0.f, 0.f, 0.f, 0.f};
    f32x4 acc1 = {0.f, 0.f, 0.f, 0.f};

#pragma unroll 4
    for (int s = 0; s < 16; ++s) {
        const float4 u0 = *reinterpret_cast<const float4*>(xr + s * 32);
        const float4 u1 = *reinterpret_cast<const float4*>(xr + s * 32 + 4);
        const short8v b0h = __builtin_bit_cast(short8v, bh[(long)(s * 2    ) * 64]);
        const short8v b1h = __builtin_bit_cast(short8v, bh[(long)(s * 2 + 1) * 64]);
        const short8v b0l = __builtin_bit_cast(short8v, bl[(long)(s * 2    ) * 64]);
        const short8v b1l = __builtin_bit_cast(short8v, bl[(long)(s * 2 + 1) * 64]);

        const float xf[8] = {u0.x, u0.y, u0.z, u0.w, u1.x, u1.y, u1.z, u1.w};
        short8v ah, al;
#pragma unroll
        for (int j = 0; j < 8; ++j) {
            const unsigned short h = f2bf(xf[j]);
            ah[j] = (short)h;
            al[j] = (short)f2bf(xf[j] - bf2f(h));
        }
        acc0 = __builtin_amdgcn_mfma_f32_16x16x32_bf16(ah, b0h, acc0, 0, 0, 0);
        acc1 = __builtin_amdgcn_mfma_f32_16x16x32_bf16(ah, b1h, acc1, 0, 0, 0);
        acc0 = __builtin_amdgcn_mfma_f32_16x16x32_bf16(al, b0h, acc0, 0, 0, 0);
        acc1 = __builtin_amdgcn_mfma_f32_16x16x32_bf16(al, b1h, acc1, 0, 0, 0);
        acc0 = __builtin_amdgcn_mfma_f32_16x16x32_bf16(ah, b0l, acc0, 0, 0, 0);
        acc1 = __builtin_amdgcn_mfma_f32_16x16x32_bf16(ah, b1l, acc1, 0, 0, 0);
    }

    // C/D layout: col = lane&15, row = (lane>>4)*4 + reg  [m89]
#pragma unroll
    for (int r = 0; r < 4; ++r) {
        const long tok = tokw + kg * 4 + r;
        float* o = wsP + ((long)half * 32768 + tok) * KK + mrow;
        o[0]  = acc0[r];
        o[16] = acc1[r];
    }
}

// ============ K1b: combine 2 K-half partials + bias + epilogue + sm stats ==
__global__ __launch_bounds__(256) void k_comb2(const float* __restrict__ wsP,
    const float* __restrict__ bp, float* __restrict__ out, float* __restrict__ ws)
{
    const int blk = blockIdx.x;            // = b*16 + sc (256-token chunk)
    const int tid = threadIdx.x;
    const int wv  = __builtin_amdgcn_readfirstlane(tid >> 6);
    const long g  = (long)blk * 256 + tid;
    float acc[KK];
#pragma unroll
    for (int k = 0; k < KK; ++k) acc[k] = bp[k];
#pragma unroll
    for (int h = 0; h < 2; ++h) {
        const float4* p = reinterpret_cast<const float4*>(wsP + ((long)h * 32768 + g) * KK);
#pragma unroll
        for (int m = 0; m < 8; ++m) {
            const float4 v = p[m];
            acc[4*m]   += v.x;
            acc[4*m+1] += v.y;
            acc[4*m+2] += v.z;
            acc[4*m+3] += v.w;
        }
    }
    float4* pl = reinterpret_cast<float4*>(out + O5 + g * KK);
#pragma unroll
    for (int m = 0; m < 8; ++m)
        pl[m] = make_float4(acc[4*m], acc[4*m+1], acc[4*m+2], acc[4*m+3]);
    float rg[KK];
#pragma unroll
    for (int e = 0; e < EE; ++e) {
        const float mx = fmaxf(fmaxf(acc[4*e], acc[4*e+1]), fmaxf(acc[4*e+2], acc[4*e+3]));
        float s = 0.f;
#pragma unroll
        for (int p = 0; p < PP; ++p) { rg[4*e+p] = __expf(acc[4*e+p] - mx); s += rg[4*e+p]; }
        const float ri = 1.f / s;
#pragma unroll
        for (int p = 0; p < PP; ++p) rg[4*e+p] *= ri;
    }
    float4* prg = reinterpret_cast<float4*>(out + O6 + g * KK);
#pragma unroll
    for (int m = 0; m < 8; ++m)
        prg[m] = make_float4(rg[4*m], rg[4*m+1], rg[4*m+2], rg[4*m+3]);
    float4* pew = reinterpret_cast<float4*>(out + O0 + g * EE);
    pew[0] = make_float4(0.125f, 0.125f, 0.125f, 0.125f);
    pew[1] = make_float4(0.125f, 0.125f, 0.125f, 0.125f);
    float4* pei = reinterpret_cast<float4*>(out + O1 + g * EE);
    pei[0] = make_float4(0.f, 1.f, 2.f, 3.f);
    pei[1] = make_float4(4.f, 5.f, 6.f, 7.f);

    float m[KK];
#pragma unroll
    for (int k = 0; k < KK; ++k) m[k] = acc[k];
    for (int off = 1; off < 64; off <<= 1) {
#pragma unroll
        for (int k = 0; k < KK; ++k) m[k] = fmaxf(m[k], __shfl_xor(m[k], off));
    }
    __shared__ float lm[4][KK];
    __shared__ float lsum[4][KK];
    if ((tid & 63) == 0) {
#pragma unroll
        for (int k = 0; k < KK; ++k) lm[wv][k] = m[k];
    }
    __syncthreads();
#pragma unroll
    for (int k = 0; k < KK; ++k)
        m[k] = fmaxf(fmaxf(lm[0][k], lm[1][k]), fmaxf(lm[2][k], lm[3][k]));
    float sv[KK];
#pragma unroll
    for (int k = 0; k < KK; ++k) sv[k] = __expf(acc[k] - m[k]);
    for (int off = 1; off < 64; off <<= 1) {
#pragma unroll
        for (int k = 0; k < KK; ++k) sv[k] += __shfl_xor(sv[k], off);
    }
    if ((tid & 63) == 0) {
#pragma unroll
        for (int k = 0; k < KK; ++k) lsum[wv][k] = sv[k];
    }
    __syncthreads();
    if (tid == 0) {
#pragma unroll
        for (int k = 0; k < KK; ++k) {
            ws[WA + (long)blk * 64 + k]      = m[k];
            ws[WA + (long)blk * 64 + 32 + k] = lsum[0][k] + lsum[1][k] + lsum[2][k] + lsum[3][k];
        }
    }
}

// ============ K2: pw + A-fragment pack (folds stat combine) ================
__global__ __launch_bounds__(256) void k_pwfrag(float* __restrict__ out,
    const float* __restrict__ ws, unsigned short* __restrict__ fh,
    unsigned short* __restrict__ fl)
{
    const int blk = blockIdx.x;           // b*128 + cs
    const int b  = blk >> 7;
    const int t  = threadIdx.x;
    const int h  = t >> 7;
    const int l  = (t >> 1) & 63;
    const int jh = t & 1;
    const int k  = h * 16 + (l & 15);
    const long sbase = (long)(blk & 127) * 32 + ((l >> 4) << 3) + jh * 4;

    float m = -1e30f, s = 0.f;
#pragma unroll
    for (int c = 0; c < 16; ++c) {
        const float mc = ws[WA + (long)(b * 16 + c) * 64 + k];
        const float sc = ws[WA + (long)(b * 16 + c) * 64 + 32 + k];
        const float nm = fmaxf(m, mc);
        s = s * __expf(m - nm) + sc * __expf(mc - nm);
        m = nm;
    }
    const float rv = 1.f / s;

    unsigned short hh[4], ll[4];
#pragma unroll
    for (int j2 = 0; j2 < 4; ++j2) {
        const long sg = (long)b * SS + sbase + j2;
        const float lg = out[O5 + sg * KK + k];
        const float pw = __expf(lg - m) * rv;
        out[O2 + sg * KK + k] = pw;
        const unsigned u = __builtin_bit_cast(unsigned, pw);
        hh[j2] = (unsigned short)(u >> 16);
        const float hi = __builtin_bit_cast(float, u & 0xFFFF0000u);
        ll[j2] = (unsigned short)(__builtin_bit_cast(unsigned, pw - hi) >> 16);
    }
    const long fb = (((long)blk * 2 + h) * 64 + l) * 8 + jh * 4;
    *reinterpret_cast<uint2*>(fh + fb) =
        make_uint2((unsigned)hh[0] | ((unsigned)hh[1] << 16),
                   (unsigned)hh[2] | ((unsigned)hh[3] << 16));
    *reinterpret_cast<uint2*>(fl + fb) =
        make_uint2((unsigned)ll[0] | ((unsigned)ll[1] << 16),
                   (unsigned)ll[2] | ((unsigned)ll[3] << 16));
}

// ============ K3: MFMA soft-slots GEMM (SC=16 for TLP) =====================
__global__ __launch_bounds__(256) void k_slots_mfma(const float* __restrict__ x,
    const unsigned short* __restrict__ fh, const unsigned short* __restrict__ fl,
    float* __restrict__ dst, int SC, int SLEN)
{
    const int tid  = threadIdx.x;
    const int wv   = tid >> 6;
    const int lane = tid & 63;
    const int blk  = blockIdx.x;
    const int sc   = blk % SC;
    const int t2   = blk / SC;
    const int dt   = t2 & 15;
    const int b    = t2 >> 4;
    const int d0   = dt * 64 + wv * 16;
    const int n    = lane & 15;
    const int kg   = lane >> 4;
    const int CPS  = SLEN >> 5;

    const float* xb = x + ((long)b * SS + (long)sc * SLEN) * DD + d0 + n;
    const uint4* FH = reinterpret_cast<const uint4*>(fh);
    const uint4* FL = reinterpret_cast<const uint4*>(fl);

    f32x4 a0 = {0.f, 0.f, 0.f, 0.f};
    f32x4 a1 = {0.f, 0.f, 0.f, 0.f};

#pragma unroll 2
    for (int c = 0; c < CPS; ++c) {
        float xf[8];
#pragma unroll
        for (int j = 0; j < 8; ++j)
            xf[j] = xb[(long)(c * 32 + kg * 8 + j) * DD];
        short8v xh, xl;
#pragma unroll
        for (int j = 0; j < 8; ++j) {
            const unsigned u = __builtin_bit_cast(unsigned, xf[j]);
            xh[j] = (short)(u >> 16);
            const float hi = __builtin_bit_cast(float, u & 0xFFFF0000u);
            xl[j] = (short)(__builtin_bit_cast(unsigned, xf[j] - hi) >> 16);
        }
        const long fidx = ((long)(b * 128 + sc * CPS + c) * 2) * 64 + lane;
        const short8v p0h = __builtin_bit_cast(short8v, FH[fidx]);
        const short8v p0l = __builtin_bit_cast(short8v, FL[fidx]);
        const short8v p1h = __builtin_bit_cast(short8v, FH[fidx + 64]);
        const short8v p1l = __builtin_bit_cast(short8v, FL[fidx + 64]);

        a0 = __builtin_amdgcn_mfma_f32_16x16x32_bf16(p0h, xh, a0, 0, 0, 0);
        a1 = __builtin_amdgcn_mfma_f32_16x16x32_bf16(p1h, xh, a1, 0, 0, 0);
        a0 = __builtin_amdgcn_mfma_f32_16x16x32_bf16(p0l, xh, a0, 0, 0, 0);
        a1 = __builtin_amdgcn_mfma_f32_16x16x32_bf16(p1l, xh, a1, 0, 0, 0);
        a0 = __builtin_amdgcn_mfma_f32_16x16x32_bf16(p0h, xl, a0, 0, 0, 0);
        a1 = __builtin_amdgcn_mfma_f32_16x16x32_bf16(p1h, xl, a1, 0, 0, 0);
    }

    // C/D: slot = (lane>>4)*4 + r (+16 for a1), d = d0 + (lane&15)  [m89]
    float* ob = dst + ((long)(sc * BB + b) * KK) * DD + d0 + n;
#pragma unroll
    for (int r = 0; r < 4; ++r) {
        ob[(long)((kg << 2) + r) * DD]        = a0[r];
        ob[(long)(16 + (kg << 2) + r) * DD]   = a1[r];
    }
}

// ============ K4: reduce SC partials -> soft_slots + expert_inputs =========
__global__ __launch_bounds__(256) void k_red(const float* __restrict__ src,
                                             float* __restrict__ out, int SC)
{
    const long i4 = (long)blockIdx.x * 256 + threadIdx.x;
    float4 s = make_float4(0.f, 0.f, 0.f, 0.f);
    const float4* p = reinterpret_cast<const float4*>(src);
    for (int c = 0; c < SC; ++c) {
        const float4 t = p[(long)c * 65536 + i4];
        s.x += t.x; s.y += t.y; s.z += t.z; s.w += t.w;
    }
    reinterpret_cast<float4*>(out + O3)[i4] = s;
    reinterpret_cast<float4*>(out + O4)[i4] = s;
}

// ===================== fallback path (tiny workspace) ======================
__global__ __launch_bounds__(256) void k_logits4(const float* __restrict__ x,
    const float* __restrict__ Wp, const float* __restrict__ bp,
    float* __restrict__ out)
{
    __shared__ float xl[2][64][68];
    __shared__ float wl[2][64][32];
    const int tid  = threadIdx.x;
    const int wv   = __builtin_amdgcn_readfirstlane(tid >> 6);
    const int lane = tid & 63;
    const long tok0 = (long)blockIdx.x * 64;
    const long g   = tok0 + lane;
    const int sr = tid >> 2;
    const int sco = (tid & 3) * 4;
    float acc[8];
#pragma unroll
    for (int j = 0; j < 8; ++j) acc[j] = 0.f;
    float4 xr[4], wr[2];
#pragma unroll
    for (int j = 0; j < 4; ++j)
        xr[j] = *reinterpret_cast<const float4*>(x + (tok0 + sr) * DD + sco + j * 16);
#pragma unroll
    for (int j = 0; j < 2; ++j)
        wr[j] = *reinterpret_cast<const float4*>(Wp + tid * 8 + j * 4);
#pragma unroll
    for (int j = 0; j < 4; ++j)
        *reinterpret_cast<float4*>(&xl[0][sr][sco + j * 16]) = xr[j];
#pragma unroll
    for (int j = 0; j < 2; ++j)
        *reinterpret_cast<float4*>(&wl[0][0][0] + tid * 8 + j * 4) = wr[j];
    __syncthreads();
    for (int c = 0; c < 16; ++c) {
        const int cb = c & 1;
        if (c < 15) {
            const long dg = (long)(c + 1) * 64;
#pragma unroll
            for (int j = 0; j < 4; ++j)
                xr[j] = *reinterpret_cast<const float4*>(
                    x + (tok0 + sr) * DD + dg + sco + j * 16);
#pragma unroll
            for (int j = 0; j < 2; ++j)
                wr[j] = *reinterpret_cast<const float4*>(Wp + dg * KK + tid * 8 + j * 4);
        }
        const float* xb = &xl[cb][lane][0];
        const float* wb = &wl[cb][0][0] + wv * 8;
#pragma unroll 4
        for (int dq = 0; dq < 16; ++dq) {
            const float4 xv = *reinterpret_cast<const float4*>(xb + dq * 4);
#pragma unroll
            for (int dd = 0; dd < 4; ++dd) {
                const float xs = (dd == 0) ? xv.x : (dd == 1) ? xv.y
                               : (dd == 2) ? xv.z : xv.w;
                const float4 w0 = *reinterpret_cast<const float4*>(wb + (dq * 4 + dd) * 32);
                const float4 w1 = *reinterpret_cast<const float4*>(wb + (dq * 4 + dd) * 32 + 4);
                acc[0] = fmaf(xs, w0.x, acc[0]);
                acc[1] = fmaf(xs, w0.y, acc[1]);
                acc[2] = fmaf(xs, w0.z, acc[2]);
                acc[3] = fmaf(xs, w0.w, acc[3]);
                acc[4] = fmaf(xs, w1.x, acc[4]);
                acc[5] = fmaf(xs, w1.y, acc[5]);
                acc[6] = fmaf(xs, w1.z, acc[6]);
                acc[7] = fmaf(xs, w1.w, acc[7]);
            }
        }
        if (c < 15) {
#pragma unroll
            for (int j = 0; j < 4; ++j)
                *reinterpret_cast<float4*>(&xl[cb ^ 1][sr][sco + j * 16]) = xr[j];
#pragma unroll
            for (int j = 0; j < 2; ++j)
                *reinterpret_cast<float4*>(&wl[cb ^ 1][0][0] + tid * 8 + j * 4) = wr[j];
        }
        __syncthreads();
    }
#pragma unroll
    for (int j = 0; j < 8; ++j) acc[j] += bp[wv * 8 + j];
    float* o5 = out + O5 + g * KK + wv * 8;
    *reinterpret_cast<float4*>(o5)     = make_float4(acc[0], acc[1], acc[2], acc[3]);
    *reinterpret_cast<float4*>(o5 + 4) = make_float4(acc[4], acc[5], acc[6], acc[7]);
    float rg[8];
#pragma unroll
    for (int e = 0; e < 2; ++e) {
        const float* aa = &acc[e * 4];
        const float m = fmaxf(fmaxf(aa[0], aa[1]), fmaxf(aa[2], aa[3]));
        float s = 0.f;
#pragma unroll
        for (int p = 0; p < PP; ++p) { rg[e*4+p] = __expf(aa[p] - m); s += rg[e*4+p]; }
        const float ri = 1.f / s;
#pragma unroll
        for (int p = 0; p < PP; ++p) rg[e*4+p] *= ri;
    }
    float* o6 = out + O6 + g * KK + wv * 8;
    *reinterpret_cast<float4*>(o6)     = make_float4(rg[0], rg[1], rg[2], rg[3]);
    *reinterpret_cast<float4*>(o6 + 4) = make_float4(rg[4], rg[5], rg[6], rg[7]);
    if (wv == 0) {
        float4* p = reinterpret_cast<float4*>(out + O0 + g * EE);
        p[0] = make_float4(0.125f, 0.125f, 0.125f, 0.125f);
        p[1] = make_float4(0.125f, 0.125f, 0.125f, 0.125f);
    } else if (wv == 1) {
        float4* p = reinterpret_cast<float4*>(out + O1 + g * EE);
        p[0] = make_float4(0.f, 1.f, 2.f, 3.f);
        p[1] = make_float4(4.f, 5.f, 6.f, 7.f);
    }
}

__global__ __launch_bounds__(256) void k_smpart(const float* __restrict__ out,
                                                float* __restrict__ ws)
{
    const int blk = blockIdx.x;
    const int tid = threadIdx.x;
    const int wv  = __builtin_amdgcn_readfirstlane(tid >> 6);
    const int b = blk >> 4, sc = blk & 15;
    const long s  = (long)sc * 256 + tid;
    const float* row = out + O5 + ((long)b * SS + s) * KK;
    float v[KK];
    const float4* r4 = reinterpret_cast<const float4*>(row);
#pragma unroll
    for (int q = 0; q < 8; ++q) {
        const float4 t = r4[q];
        v[4*q] = t.x; v[4*q+1] = t.y; v[4*q+2] = t.z; v[4*q+3] = t.w;
    }
    float m[KK];
#pragma unroll
    for (int k = 0; k < KK; ++k) m[k] = v[k];
    for (int off = 1; off < 64; off <<= 1) {
#pragma unroll
        for (int k = 0; k < KK; ++k) m[k] = fmaxf(m[k], __shfl_xor(m[k], off));
    }
    __shared__ float lm[4][KK];
    __shared__ float lsum[4][KK];
    if ((tid & 63) == 0) {
#pragma unroll
        for (int k = 0; k < KK; ++k) lm[wv][k] = m[k];
    }
    __syncthreads();
#pragma unroll
    for (int k = 0; k < KK; ++k)
        m[k] = fmaxf(fmaxf(lm[0][k], lm[1][k]), fmaxf(lm[2][k], lm[3][k]));
    float sv[KK];
#pragma unroll
    for (int k = 0; k < KK; ++k) sv[k] = __expf(v[k] - m[k]);
    for (int off = 1; off < 64; off <<= 1) {
#pragma unroll
        for (int k = 0; k < KK; ++k) sv[k] += __shfl_xor(sv[k], off);
    }
    if ((tid & 63) == 0) {
#pragma unroll
        for (int k = 0; k < KK; ++k) lsum[wv][k] = sv[k];
    }
    __syncthreads();
    if (tid == 0) {
#pragma unroll
        for (int k = 0; k < KK; ++k) {
            ws[WA + (long)blk * 64 + k]      = m[k];
            ws[WA + (long)blk * 64 + 32 + k] = lsum[0][k] + lsum[1][k] + lsum[2][k] + lsum[3][k];
        }
    }
}

__global__ __launch_bounds__(256) void k_smcomb(float* __restrict__ ws)
{
    const int tid = threadIdx.x;
    const int b = tid >> 5, k = tid & 31;
    float m = -1e30f, s = 0.f;
    for (int c = 0; c < 16; ++c) {
        const float mc = ws[WA + (long)(b * 16 + c) * 64 + k];
        const float sc = ws[WA + (long)(b * 16 + c) * 64 + 32 + k];
        const float nm = fmaxf(m, mc);
        s = s * __expf(m - nm) + sc * __expf(mc - nm);
        m = nm;
    }
    ws[WB + (long)b * 64 + k]      = m;
    ws[WB + (long)b * 64 + 32 + k] = 1.f / s;
}

__global__ __launch_bounds__(256) void k_slots2pw(const float* __restrict__ x,
    float* __restrict__ out, const float* __restrict__ ws,
    float* __restrict__ dst, int SC, int SLEN)
{
    __shared__ float pwl[2][64 * KK];
    const int tid = threadIdx.x;
    const int blk = blockIdx.x;
    const int sc  = blk % SC;
    const int t2  = blk / SC;
    const int dc  = t2 & 3;
    const int b   = t2 >> 2;
    const int d   = dc * 256 + tid;
    const int k0  = (tid & 3) * 8;

    float km[8], krv[8];
#pragma unroll
    for (int j = 0; j < 8; ++j) {
        km[j]  = ws[WB + (long)b * 64 + k0 + j];
        krv[j] = ws[WB + (long)b * 64 + 32 + k0 + j];
    }

    float acc[KK];
#pragma unroll
    for (int k = 0; k < KK; ++k) acc[k] = 0.f;
    const long s0 = (long)sc * SLEN;
    const float* lg = out + O5 + ((long)b * SS + s0) * KK;
    float* o2       = out + O2 + ((long)b * SS + s0) * KK;
    const float* xp = x + ((long)b * SS + s0) * DD + d;
    const int NCH = SLEN >> 6;

    float4 r0 = *reinterpret_cast<const float4*>(lg + tid * 8);
    float4 r1 = *reinterpret_cast<const float4*>(lg + tid * 8 + 4);
    {
        const float4 t0 = make_float4(__expf(r0.x - km[0]) * krv[0],
                                      __expf(r0.y - km[1]) * krv[1],
                                      __expf(r0.z - km[2]) * krv[2],
                                      __expf(r0.w - km[3]) * krv[3]);
        const float4 t1 = make_float4(__expf(r1.x - km[4]) * krv[4],
                                      __expf(r1.y - km[5]) * krv[5],
                                      __expf(r1.z - km[6]) * krv[6],
                                      __expf(r1.w - km[7]) * krv[7]);
        *reinterpret_cast<float4*>(&pwl[0][tid * 8])     = t0;
        *reinterpret_cast<float4*>(&pwl[0][tid * 8 + 4]) = t1;
        if (dc == 0) {
            *reinterpret_cast<float4*>(o2 + tid * 8)     = t0;
            *reinterpret_cast<float4*>(o2 + tid * 8 + 4) = t1;
        }
    }
    __syncthreads();

    for (int ch = 0; ch < NCH; ++ch) {
        const int cb = ch & 1;
        if (ch + 1 < NCH) {
            const float* ln = lg + (long)(ch + 1) * 64 * KK;
            r0 = *reinterpret_cast<const float4*>(ln + tid * 8);
            r1 = *reinterpret_cast<const float4*>(ln + tid * 8 + 4);
        }
        const float* xc = xp + (long)ch * 64 * DD;
        const float* pb = &pwl[cb][0];
#pragma unroll 8
        for (int i = 0; i < 64; ++i) {
            const float xv = xc[(long)i * DD];
#pragma unroll
            for (int q = 0; q < 8; ++q) {
                const float4 w = *reinterpret_cast<const float4*>(pb + i * KK + q * 4);
                acc[4*q]   = fmaf(w.x, xv, acc[4*q]);
                acc[4*q+1] = fmaf(w.y, xv, acc[4*q+1]);
                acc[4*q+2] = fmaf(w.z, xv, acc[4*q+2]);
                acc[4*q+3] = fmaf(w.w, xv, acc[4*q+3]);
            }
        }
        if (ch + 1 < NCH) {
            const float4 t0 = make_float4(__expf(r0.x - km[0]) * krv[0],
                                          __expf(r0.y - km[1]) * krv[1],
                                          __expf(r0.z - km[2]) * krv[2],
                                          __expf(r0.w - km[3]) * krv[3]);
            const float4 t1 = make_float4(__expf(r1.x - km[4]) * krv[4],
                                          __expf(r1.y - km[5]) * krv[5],
                                          __expf(r1.z - km[6]) * krv[6],
                                          __expf(r1.w - km[7]) * krv[7]);
            *reinterpret_cast<float4*>(&pwl[cb ^ 1][tid * 8])     = t0;
            *reinterpret_cast<float4*>(&pwl[cb ^ 1][tid * 8 + 4]) = t1;
            if (dc == 0) {
                float* on = o2 + (long)(ch + 1) * 64 * KK;
                *reinterpret_cast<float4*>(on + tid * 8)     = t0;
                *reinterpret_cast<float4*>(on + tid * 8 + 4) = t1;
            }
        }
        __syncthreads();
    }
    float* o = dst + ((long)(sc * BB + b) * KK) * DD + d;
#pragma unroll
    for (int k = 0; k < KK; ++k) o[(long)k * DD] = acc[k];
}

extern "C" void kernel_launch(void* const* d_in, const int* in_sizes, int n_in,
                              void* d_out, int out_size, void* d_ws, size_t ws_size,
                              hipStream_t stream)
{
    const float* x  = (const float*)d_in[0];
    const float* Wp = (const float*)d_in[1];
    const float* bp = (const float*)d_in[2];
    float* out = (float*)d_out;
    float* ws  = (float*)d_ws;

    const size_t wfloats = ws_size / 4;
    const long need = WC2 + 16L * 262144;   // 21.3 MB total
    const bool mfma_ok = wfloats >= (size_t)need;

    if (mfma_ok) {
        unsigned short* wh = (unsigned short*)(ws + WPKH);
        unsigned short* wl = (unsigned short*)(ws + WPKL);
        unsigned short* fh = (unsigned short*)(ws + PWFH);
        unsigned short* fl = (unsigned short*)(ws + PWFL);
        hipLaunchKernelGGL(k_wprep,       dim3(16),   dim3(256), 0, stream, Wp, wh, wl);
        hipLaunchKernelGGL(k_logits_mfma, dim3(1024), dim3(256), 0, stream, x, wh, wl, ws + WC2);
        hipLaunchKernelGGL(k_comb2,       dim3(128),  dim3(256), 0, stream, ws + WC2, bp, out, ws);
        hipLaunchKernelGGL(k_pwfrag,      dim3(1024), dim3(256), 0, stream, out, ws, fh, fl);
        hipLaunchKernelGGL(k_slots_mfma,  dim3(BB * 16 * 16), dim3(256), 0, stream,
                           x, fh, fl, ws + WC2, 16, SS / 16);
        hipLaunchKernelGGL(k_red,         dim3(256),  dim3(256), 0, stream, ws + WC2, out, 16);
    } else {
        hipLaunchKernelGGL(k_logits4, dim3(512), dim3(256), 0, stream, x, Wp, bp, out);
        hipLaunchKernelGGL(k_smpart,  dim3(128), dim3(256), 0, stream, out, ws);
        hipLaunchKernelGGL(k_smcomb,  dim3(1),   dim3(256), 0, stream, ws);
        int SC = 0;
        if      (wfloats >= (size_t)(WC2 + 8L * 262144)) SC = 8;
        else if (wfloats >= (size_t)(WC2 + 4L * 262144)) SC = 4;
        else if (wfloats >= (size_t)(WC2 + 2L * 262144)) SC = 2;
        else if (wfloats >= (size_t)(WC2 + 1L * 262144)) SC = 1;
        if (SC >= 1) {
            hipLaunchKernelGGL(k_slots2pw, dim3(BB * 4 * SC), dim3(256), 0, stream,
                               x, out, ws, ws + WC2, SC, SS / SC);
            hipLaunchKernelGGL(k_red, dim3(256), dim3(256), 0, stream, ws + WC2, out, SC);
        } else {
            hipLaunchKernelGGL(k_slots2pw, dim3(BB * 4), dim3(256), 0, stream,
                               x, out, ws, out + O3, 1, SS);
            hipLaunchKernelGGL(k_red, dim3(256), dim3(256), 0, stream, out + O3, out, 1);
        }
    }
}

// Round 20
// 87.249 us; speedup vs baseline: 1.0341x; 1.0341x over previous
//
#include <hip/hip_runtime.h>
#include <hip/hip_bf16.h>

#define BB 8
#define SS 4096
#define DD 1024
#define KK 32
#define EE 8
#define PP 4

// ---- output float offsets ----
#define O0 0L
#define O1 262144L
#define O2 524288L
#define O3 1572864L
#define O4 1835008L
#define O5 2097152L
#define O6 3145728L

// ---- workspace float offsets ----
#define WA 0L            // per-chunk sm stats: 128 chunks * 64
#define WB 8192L         // final m / 1/sum per (b,k) (fallback path)
#define WPKH 16384L      // W packed hi: 32768 ushort = 16384 floats
#define WPKL 32768L      // W packed lo
#define PWFH 49152L      // pw frags hi: 1M ushort = 524288 floats
#define PWFL 573440L     // pw frags lo
#define WC2 1097728L     // logits partials (8.4MB) THEN slots partials (8.4MB)

typedef __attribute__((ext_vector_type(8))) short short8v;
typedef __attribute__((ext_vector_type(4))) float f32x4;

__device__ __forceinline__ unsigned short f2bf(float f) {
    unsigned u = __builtin_bit_cast(unsigned, f);
    unsigned r = (u + 0x7FFFu + ((u >> 16) & 1u)) >> 16;
    return (unsigned short)r;
}
__device__ __forceinline__ float bf2f(unsigned short h) {
    return __builtin_bit_cast(float, (unsigned)h << 16);
}

// ============ K0: pack W into B^T-fragment order, bf16 hi+lo ==============
__global__ __launch_bounds__(256) void k_wprep(const float* __restrict__ Wp,
    unsigned short* __restrict__ wh, unsigned short* __restrict__ wl)
{
    const int t  = blockIdx.x * 256 + threadIdx.x;
    const int l  = t & 63;
    const int tt = (t >> 6) & 1;
    const int ks = t >> 7;
    const int col = tt * 16 + (l & 15);
    const int dbase = ks * 32 + (l >> 4) * 8;
    const long obase = ((long)(ks * 2 + tt) * 64 + l) * 8;
#pragma unroll
    for (int j = 0; j < 8; ++j) {
        const float w = Wp[(long)(dbase + j) * KK + col];
        const unsigned short h = f2bf(w);
        const float lo = w - bf2f(h);
        wh[obase + j] = h;
        wl[obase + j] = f2bf(lo);
    }
}

// ============ K1: MFMA logits GEMM (2 K-halves, grid 1024) =================
__global__ __launch_bounds__(256) void k_logits_mfma(const float* __restrict__ x,
    const unsigned short* __restrict__ wh, const unsigned short* __restrict__ wl,
    float* __restrict__ wsP)
{
    const int tid  = threadIdx.x;
    const int wv   = tid >> 6;
    const int lane = tid & 63;
    const int blk  = blockIdx.x;
    const int tile = blk >> 1, half = blk & 1;
    const long tokw = (long)tile * 64 + wv * 16;
    const int mrow = lane & 15;
    const int kg   = lane >> 4;

    const float* xr = x + (tokw + mrow) * DD + half * 512 + kg * 8;
    const uint4* bh = reinterpret_cast<const uint4*>(wh) + (long)half * 16 * 2 * 64 + lane;
    const uint4* bl = reinterpret_cast<const uint4*>(wl) + (long)half * 16 * 2 * 64 + lane;

    f32x4 acc0 = {0.f, 0.f, 0.f, 0.f};
    f32x4 acc1 = {0.f, 0.f, 0.f, 0.f};

#pragma unroll 4
    for (int s = 0; s < 16; ++s) {
        const float4 u0 = *reinterpret_cast<const float4*>(xr + s * 32);
        const float4 u1 = *reinterpret_cast<const float4*>(xr + s * 32 + 4);
        const short8v b0h = __builtin_bit_cast(short8v, bh[(long)(s * 2    ) * 64]);
        const short8v b1h = __builtin_bit_cast(short8v, bh[(long)(s * 2 + 1) * 64]);
        const short8v b0l = __builtin_bit_cast(short8v, bl[(long)(s * 2    ) * 64]);
        const short8v b1l = __builtin_bit_cast(short8v, bl[(long)(s * 2 + 1) * 64]);

        const float xf[8] = {u0.x, u0.y, u0.z, u0.w, u1.x, u1.y, u1.z, u1.w};
        short8v ah, al;
#pragma unroll
        for (int j = 0; j < 8; ++j) {
            const unsigned short h = f2bf(xf[j]);
            ah[j] = (short)h;
            al[j] = (short)f2bf(xf[j] - bf2f(h));
        }
        acc0 = __builtin_amdgcn_mfma_f32_16x16x32_bf16(ah, b0h, acc0, 0, 0, 0);
        acc1 = __builtin_amdgcn_mfma_f32_16x16x32_bf16(ah, b1h, acc1, 0, 0, 0);
        acc0 = __builtin_amdgcn_mfma_f32_16x16x32_bf16(al, b0h, acc0, 0, 0, 0);
        acc1 = __builtin_amdgcn_mfma_f32_16x16x32_bf16(al, b1h, acc1, 0, 0, 0);
        acc0 = __builtin_amdgcn_mfma_f32_16x16x32_bf16(ah, b0l, acc0, 0, 0, 0);
        acc1 = __builtin_amdgcn_mfma_f32_16x16x32_bf16(ah, b1l, acc1, 0, 0, 0);
    }

    // C/D layout: col = lane&15, row = (lane>>4)*4 + reg  [m89]
#pragma unroll
    for (int r = 0; r < 4; ++r) {
        const long tok = tokw + kg * 4 + r;
        float* o = wsP + ((long)half * 32768 + tok) * KK + mrow;
        o[0]  = acc0[r];
        o[16] = acc1[r];
    }
}

// ============ K1b: combine 2 K-half partials + bias + epilogue + sm stats ==
__global__ __launch_bounds__(256) void k_comb2(const float* __restrict__ wsP,
    const float* __restrict__ bp, float* __restrict__ out, float* __restrict__ ws)
{
    const int blk = blockIdx.x;            // = b*16 + sc (256-token chunk)
    const int tid = threadIdx.x;
    const int wv  = __builtin_amdgcn_readfirstlane(tid >> 6);
    const long g  = (long)blk * 256 + tid;
    float acc[KK];
#pragma unroll
    for (int k = 0; k < KK; ++k) acc[k] = bp[k];
#pragma unroll
    for (int h = 0; h < 2; ++h) {
        const float4* p = reinterpret_cast<const float4*>(wsP + ((long)h * 32768 + g) * KK);
#pragma unroll
        for (int m = 0; m < 8; ++m) {
            const float4 v = p[m];
            acc[4*m]   += v.x;
            acc[4*m+1] += v.y;
            acc[4*m+2] += v.z;
            acc[4*m+3] += v.w;
        }
    }
    float4* pl = reinterpret_cast<float4*>(out + O5 + g * KK);
#pragma unroll
    for (int m = 0; m < 8; ++m)
        pl[m] = make_float4(acc[4*m], acc[4*m+1], acc[4*m+2], acc[4*m+3]);
    float rg[KK];
#pragma unroll
    for (int e = 0; e < EE; ++e) {
        const float mx = fmaxf(fmaxf(acc[4*e], acc[4*e+1]), fmaxf(acc[4*e+2], acc[4*e+3]));
        float s = 0.f;
#pragma unroll
        for (int p = 0; p < PP; ++p) { rg[4*e+p] = __expf(acc[4*e+p] - mx); s += rg[4*e+p]; }
        const float ri = 1.f / s;
#pragma unroll
        for (int p = 0; p < PP; ++p) rg[4*e+p] *= ri;
    }
    float4* prg = reinterpret_cast<float4*>(out + O6 + g * KK);
#pragma unroll
    for (int m = 0; m < 8; ++m)
        prg[m] = make_float4(rg[4*m], rg[4*m+1], rg[4*m+2], rg[4*m+3]);
    float4* pew = reinterpret_cast<float4*>(out + O0 + g * EE);
    pew[0] = make_float4(0.125f, 0.125f, 0.125f, 0.125f);
    pew[1] = make_float4(0.125f, 0.125f, 0.125f, 0.125f);
    float4* pei = reinterpret_cast<float4*>(out + O1 + g * EE);
    pei[0] = make_float4(0.f, 1.f, 2.f, 3.f);
    pei[1] = make_float4(4.f, 5.f, 6.f, 7.f);

    float m[KK];
#pragma unroll
    for (int k = 0; k < KK; ++k) m[k] = acc[k];
    for (int off = 1; off < 64; off <<= 1) {
#pragma unroll
        for (int k = 0; k < KK; ++k) m[k] = fmaxf(m[k], __shfl_xor(m[k], off));
    }
    __shared__ float lm[4][KK];
    __shared__ float lsum[4][KK];
    if ((tid & 63) == 0) {
#pragma unroll
        for (int k = 0; k < KK; ++k) lm[wv][k] = m[k];
    }
    __syncthreads();
#pragma unroll
    for (int k = 0; k < KK; ++k)
        m[k] = fmaxf(fmaxf(lm[0][k], lm[1][k]), fmaxf(lm[2][k], lm[3][k]));
    float sv[KK];
#pragma unroll
    for (int k = 0; k < KK; ++k) sv[k] = __expf(acc[k] - m[k]);
    for (int off = 1; off < 64; off <<= 1) {
#pragma unroll
        for (int k = 0; k < KK; ++k) sv[k] += __shfl_xor(sv[k], off);
    }
    if ((tid & 63) == 0) {
#pragma unroll
        for (int k = 0; k < KK; ++k) lsum[wv][k] = sv[k];
    }
    __syncthreads();
    if (tid == 0) {
#pragma unroll
        for (int k = 0; k < KK; ++k) {
            ws[WA + (long)blk * 64 + k]      = m[k];
            ws[WA + (long)blk * 64 + 32 + k] = lsum[0][k] + lsum[1][k] + lsum[2][k] + lsum[3][k];
        }
    }
}

// ============ K2: pw + A-fragment pack (folds stat combine) ================
__global__ __launch_bounds__(256) void k_pwfrag(float* __restrict__ out,
    const float* __restrict__ ws, unsigned short* __restrict__ fh,
    unsigned short* __restrict__ fl)
{
    const int blk = blockIdx.x;           // b*128 + cs
    const int b  = blk >> 7;
    const int t  = threadIdx.x;
    const int h  = t >> 7;
    const int l  = (t >> 1) & 63;
    const int jh = t & 1;
    const int k  = h * 16 + (l & 15);
    const long sbase = (long)(blk & 127) * 32 + ((l >> 4) << 3) + jh * 4;

    float m = -1e30f, s = 0.f;
#pragma unroll
    for (int c = 0; c < 16; ++c) {
        const float mc = ws[WA + (long)(b * 16 + c) * 64 + k];
        const float sc = ws[WA + (long)(b * 16 + c) * 64 + 32 + k];
        const float nm = fmaxf(m, mc);
        s = s * __expf(m - nm) + sc * __expf(mc - nm);
        m = nm;
    }
    const float rv = 1.f / s;

    unsigned short hh[4], ll[4];
#pragma unroll
    for (int j2 = 0; j2 < 4; ++j2) {
        const long sg = (long)b * SS + sbase + j2;
        const float lg = out[O5 + sg * KK + k];
        const float pw = __expf(lg - m) * rv;
        out[O2 + sg * KK + k] = pw;
        const unsigned u = __builtin_bit_cast(unsigned, pw);
        hh[j2] = (unsigned short)(u >> 16);
        const float hi = __builtin_bit_cast(float, u & 0xFFFF0000u);
        ll[j2] = (unsigned short)(__builtin_bit_cast(unsigned, pw - hi) >> 16);
    }
    const long fb = (((long)blk * 2 + h) * 64 + l) * 8 + jh * 4;
    *reinterpret_cast<uint2*>(fh + fb) =
        make_uint2((unsigned)hh[0] | ((unsigned)hh[1] << 16),
                   (unsigned)hh[2] | ((unsigned)hh[3] << 16));
    *reinterpret_cast<uint2*>(fl + fb) =
        make_uint2((unsigned)ll[0] | ((unsigned)ll[1] << 16),
                   (unsigned)ll[2] | ((unsigned)ll[3] << 16));
}

// ============ K3: MFMA soft-slots GEMM (SC=8, champion config) =============
__global__ __launch_bounds__(256) void k_slots_mfma(const float* __restrict__ x,
    const unsigned short* __restrict__ fh, const unsigned short* __restrict__ fl,
    float* __restrict__ dst, int SC, int SLEN)
{
    const int tid  = threadIdx.x;
    const int wv   = tid >> 6;
    const int lane = tid & 63;
    const int blk  = blockIdx.x;
    const int sc   = blk % SC;
    const int t2   = blk / SC;
    const int dt   = t2 & 15;
    const int b    = t2 >> 4;
    const int d0   = dt * 64 + wv * 16;
    const int n    = lane & 15;
    const int kg   = lane >> 4;
    const int CPS  = SLEN >> 5;

    const float* xb = x + ((long)b * SS + (long)sc * SLEN) * DD + d0 + n;
    const uint4* FH = reinterpret_cast<const uint4*>(fh);
    const uint4* FL = reinterpret_cast<const uint4*>(fl);

    f32x4 a0 = {0.f, 0.f, 0.f, 0.f};
    f32x4 a1 = {0.f, 0.f, 0.f, 0.f};

#pragma unroll 2
    for (int c = 0; c < CPS; ++c) {
        float xf[8];
#pragma unroll
        for (int j = 0; j < 8; ++j)
            xf[j] = xb[(long)(c * 32 + kg * 8 + j) * DD];
        short8v xh, xl;
#pragma unroll
        for (int j = 0; j < 8; ++j) {
            const unsigned u = __builtin_bit_cast(unsigned, xf[j]);
            xh[j] = (short)(u >> 16);
            const float hi = __builtin_bit_cast(float, u & 0xFFFF0000u);
            xl[j] = (short)(__builtin_bit_cast(unsigned, xf[j] - hi) >> 16);
        }
        const long fidx = ((long)(b * 128 + sc * CPS + c) * 2) * 64 + lane;
        const short8v p0h = __builtin_bit_cast(short8v, FH[fidx]);
        const short8v p0l = __builtin_bit_cast(short8v, FL[fidx]);
        const short8v p1h = __builtin_bit_cast(short8v, FH[fidx + 64]);
        const short8v p1l = __builtin_bit_cast(short8v, FL[fidx + 64]);

        a0 = __builtin_amdgcn_mfma_f32_16x16x32_bf16(p0h, xh, a0, 0, 0, 0);
        a1 = __builtin_amdgcn_mfma_f32_16x16x32_bf16(p1h, xh, a1, 0, 0, 0);
        a0 = __builtin_amdgcn_mfma_f32_16x16x32_bf16(p0l, xh, a0, 0, 0, 0);
        a1 = __builtin_amdgcn_mfma_f32_16x16x32_bf16(p1l, xh, a1, 0, 0, 0);
        a0 = __builtin_amdgcn_mfma_f32_16x16x32_bf16(p0h, xl, a0, 0, 0, 0);
        a1 = __builtin_amdgcn_mfma_f32_16x16x32_bf16(p1h, xl, a1, 0, 0, 0);
    }

    // C/D: slot = (lane>>4)*4 + r (+16 for a1), d = d0 + (lane&15)  [m89]
    float* ob = dst + ((long)(sc * BB + b) * KK) * DD + d0 + n;
#pragma unroll
    for (int r = 0; r < 4; ++r) {
        ob[(long)((kg << 2) + r) * DD]        = a0[r];
        ob[(long)(16 + (kg << 2) + r) * DD]   = a1[r];
    }
}

// ============ K4: reduce SC partials -> soft_slots + expert_inputs =========
__global__ __launch_bounds__(256) void k_red(const float* __restrict__ src,
                                             float* __restrict__ out, int SC)
{
    const long i4 = (long)blockIdx.x * 256 + threadIdx.x;
    float4 s = make_float4(0.f, 0.f, 0.f, 0.f);
    const float4* p = reinterpret_cast<const float4*>(src);
    for (int c = 0; c < SC; ++c) {
        const float4 t = p[(long)c * 65536 + i4];
        s.x += t.x; s.y += t.y; s.z += t.z; s.w += t.w;
    }
    reinterpret_cast<float4*>(out + O3)[i4] = s;
    reinterpret_cast<float4*>(out + O4)[i4] = s;
}

// ===================== fallback path (tiny workspace) ======================
__global__ __launch_bounds__(256) void k_logits4(const float* __restrict__ x,
    const float* __restrict__ Wp, const float* __restrict__ bp,
    float* __restrict__ out)
{
    __shared__ float xl[2][64][68];
    __shared__ float wl[2][64][32];
    const int tid  = threadIdx.x;
    const int wv   = __builtin_amdgcn_readfirstlane(tid >> 6);
    const int lane = tid & 63;
    const long tok0 = (long)blockIdx.x * 64;
    const long g   = tok0 + lane;
    const int sr = tid >> 2;
    const int sco = (tid & 3) * 4;
    float acc[8];
#pragma unroll
    for (int j = 0; j < 8; ++j) acc[j] = 0.f;
    float4 xr[4], wr[2];
#pragma unroll
    for (int j = 0; j < 4; ++j)
        xr[j] = *reinterpret_cast<const float4*>(x + (tok0 + sr) * DD + sco + j * 16);
#pragma unroll
    for (int j = 0; j < 2; ++j)
        wr[j] = *reinterpret_cast<const float4*>(Wp + tid * 8 + j * 4);
#pragma unroll
    for (int j = 0; j < 4; ++j)
        *reinterpret_cast<float4*>(&xl[0][sr][sco + j * 16]) = xr[j];
#pragma unroll
    for (int j = 0; j < 2; ++j)
        *reinterpret_cast<float4*>(&wl[0][0][0] + tid * 8 + j * 4) = wr[j];
    __syncthreads();
    for (int c = 0; c < 16; ++c) {
        const int cb = c & 1;
        if (c < 15) {
            const long dg = (long)(c + 1) * 64;
#pragma unroll
            for (int j = 0; j < 4; ++j)
                xr[j] = *reinterpret_cast<const float4*>(
                    x + (tok0 + sr) * DD + dg + sco + j * 16);
#pragma unroll
            for (int j = 0; j < 2; ++j)
                wr[j] = *reinterpret_cast<const float4*>(Wp + dg * KK + tid * 8 + j * 4);
        }
        const float* xb = &xl[cb][lane][0];
        const float* wb = &wl[cb][0][0] + wv * 8;
#pragma unroll 4
        for (int dq = 0; dq < 16; ++dq) {
            const float4 xv = *reinterpret_cast<const float4*>(xb + dq * 4);
#pragma unroll
            for (int dd = 0; dd < 4; ++dd) {
                const float xs = (dd == 0) ? xv.x : (dd == 1) ? xv.y
                               : (dd == 2) ? xv.z : xv.w;
                const float4 w0 = *reinterpret_cast<const float4*>(wb + (dq * 4 + dd) * 32);
                const float4 w1 = *reinterpret_cast<const float4*>(wb + (dq * 4 + dd) * 32 + 4);
                acc[0] = fmaf(xs, w0.x, acc[0]);
                acc[1] = fmaf(xs, w0.y, acc[1]);
                acc[2] = fmaf(xs, w0.z, acc[2]);
                acc[3] = fmaf(xs, w0.w, acc[3]);
                acc[4] = fmaf(xs, w1.x, acc[4]);
                acc[5] = fmaf(xs, w1.y, acc[5]);
                acc[6] = fmaf(xs, w1.z, acc[6]);
                acc[7] = fmaf(xs, w1.w, acc[7]);
            }
        }
        if (c < 15) {
#pragma unroll
            for (int j = 0; j < 4; ++j)
                *reinterpret_cast<float4*>(&xl[cb ^ 1][sr][sco + j * 16]) = xr[j];
#pragma unroll
            for (int j = 0; j < 2; ++j)
                *reinterpret_cast<float4*>(&wl[cb ^ 1][0][0] + tid * 8 + j * 4) = wr[j];
        }
        __syncthreads();
    }
#pragma unroll
    for (int j = 0; j < 8; ++j) acc[j] += bp[wv * 8 + j];
    float* o5 = out + O5 + g * KK + wv * 8;
    *reinterpret_cast<float4*>(o5)     = make_float4(acc[0], acc[1], acc[2], acc[3]);
    *reinterpret_cast<float4*>(o5 + 4) = make_float4(acc[4], acc[5], acc[6], acc[7]);
    float rg[8];
#pragma unroll
    for (int e = 0; e < 2; ++e) {
        const float* aa = &acc[e * 4];
        const float m = fmaxf(fmaxf(aa[0], aa[1]), fmaxf(aa[2], aa[3]));
        float s = 0.f;
#pragma unroll
        for (int p = 0; p < PP; ++p) { rg[e*4+p] = __expf(aa[p] - m); s += rg[e*4+p]; }
        const float ri = 1.f / s;
#pragma unroll
        for (int p = 0; p < PP; ++p) rg[e*4+p] *= ri;
    }
    float* o6 = out + O6 + g * KK + wv * 8;
    *reinterpret_cast<float4*>(o6)     = make_float4(rg[0], rg[1], rg[2], rg[3]);
    *reinterpret_cast<float4*>(o6 + 4) = make_float4(rg[4], rg[5], rg[6], rg[7]);
    if (wv == 0) {
        float4* p = reinterpret_cast<float4*>(out + O0 + g * EE);
        p[0] = make_float4(0.125f, 0.125f, 0.125f, 0.125f);
        p[1] = make_float4(0.125f, 0.125f, 0.125f, 0.125f);
    } else if (wv == 1) {
        float4* p = reinterpret_cast<float4*>(out + O1 + g * EE);
        p[0] = make_float4(0.f, 1.f, 2.f, 3.f);
        p[1] = make_float4(4.f, 5.f, 6.f, 7.f);
    }
}

__global__ __launch_bounds__(256) void k_smpart(const float* __restrict__ out,
                                                float* __restrict__ ws)
{
    const int blk = blockIdx.x;
    const int tid = threadIdx.x;
    const int wv  = __builtin_amdgcn_readfirstlane(tid >> 6);
    const int b = blk >> 4, sc = blk & 15;
    const long s  = (long)sc * 256 + tid;
    const float* row = out + O5 + ((long)b * SS + s) * KK;
    float v[KK];
    const float4* r4 = reinterpret_cast<const float4*>(row);
#pragma unroll
    for (int q = 0; q < 8; ++q) {
        const float4 t = r4[q];
        v[4*q] = t.x; v[4*q+1] = t.y; v[4*q+2] = t.z; v[4*q+3] = t.w;
    }
    float m[KK];
#pragma unroll
    for (int k = 0; k < KK; ++k) m[k] = v[k];
    for (int off = 1; off < 64; off <<= 1) {
#pragma unroll
        for (int k = 0; k < KK; ++k) m[k] = fmaxf(m[k], __shfl_xor(m[k], off));
    }
    __shared__ float lm[4][KK];
    __shared__ float lsum[4][KK];
    if ((tid & 63) == 0) {
#pragma unroll
        for (int k = 0; k < KK; ++k) lm[wv][k] = m[k];
    }
    __syncthreads();
#pragma unroll
    for (int k = 0; k < KK; ++k)
        m[k] = fmaxf(fmaxf(lm[0][k], lm[1][k]), fmaxf(lm[2][k], lm[3][k]));
    float sv[KK];
#pragma unroll
    for (int k = 0; k < KK; ++k) sv[k] = __expf(v[k] - m[k]);
    for (int off = 1; off < 64; off <<= 1) {
#pragma unroll
        for (int k = 0; k < KK; ++k) sv[k] += __shfl_xor(sv[k], off);
    }
    if ((tid & 63) == 0) {
#pragma unroll
        for (int k = 0; k < KK; ++k) lsum[wv][k] = sv[k];
    }
    __syncthreads();
    if (tid == 0) {
#pragma unroll
        for (int k = 0; k < KK; ++k) {
            ws[WA + (long)blk * 64 + k]      = m[k];
            ws[WA + (long)blk * 64 + 32 + k] = lsum[0][k] + lsum[1][k] + lsum[2][k] + lsum[3][k];
        }
    }
}

__global__ __launch_bounds__(256) void k_smcomb(float* __restrict__ ws)
{
    const int tid = threadIdx.x;
    const int b = tid >> 5, k = tid & 31;
    float m = -1e30f, s = 0.f;
    for (int c = 0; c < 16; ++c) {
        const float mc = ws[WA + (long)(b * 16 + c) * 64 + k];
        const float sc = ws[WA + (long)(b * 16 + c) * 64 + 32 + k];
        const float nm = fmaxf(m, mc);
        s = s * __expf(m - nm) + sc * __expf(mc - nm);
        m = nm;
    }
    ws[WB + (long)b * 64 + k]      = m;
    ws[WB + (long)b * 64 + 32 + k] = 1.f / s;
}

__global__ __launch_bounds__(256) void k_slots2pw(const float* __restrict__ x,
    float* __restrict__ out, const float* __restrict__ ws,
    float* __restrict__ dst, int SC, int SLEN)
{
    __shared__ float pwl[2][64 * KK];
    const int tid = threadIdx.x;
    const int blk = blockIdx.x;
    const int sc  = blk % SC;
    const int t2  = blk / SC;
    const int dc  = t2 & 3;
    const int b   = t2 >> 2;
    const int d   = dc * 256 + tid;
    const int k0  = (tid & 3) * 8;

    float km[8], krv[8];
#pragma unroll
    for (int j = 0; j < 8; ++j) {
        km[j]  = ws[WB + (long)b * 64 + k0 + j];
        krv[j] = ws[WB + (long)b * 64 + 32 + k0 + j];
    }

    float acc[KK];
#pragma unroll
    for (int k = 0; k < KK; ++k) acc[k] = 0.f;
    const long s0 = (long)sc * SLEN;
    const float* lg = out + O5 + ((long)b * SS + s0) * KK;
    float* o2       = out + O2 + ((long)b * SS + s0) * KK;
    const float* xp = x + ((long)b * SS + s0) * DD + d;
    const int NCH = SLEN >> 6;

    float4 r0 = *reinterpret_cast<const float4*>(lg + tid * 8);
    float4 r1 = *reinterpret_cast<const float4*>(lg + tid * 8 + 4);
    {
        const float4 t0 = make_float4(__expf(r0.x - km[0]) * krv[0],
                                      __expf(r0.y - km[1]) * krv[1],
                                      __expf(r0.z - km[2]) * krv[2],
                                      __expf(r0.w - km[3]) * krv[3]);
        const float4 t1 = make_float4(__expf(r1.x - km[4]) * krv[4],
                                      __expf(r1.y - km[5]) * krv[5],
                                      __expf(r1.z - km[6]) * krv[6],
                                      __expf(r1.w - km[7]) * krv[7]);
        *reinterpret_cast<float4*>(&pwl[0][tid * 8])     = t0;
        *reinterpret_cast<float4*>(&pwl[0][tid * 8 + 4]) = t1;
        if (dc == 0) {
            *reinterpret_cast<float4*>(o2 + tid * 8)     = t0;
            *reinterpret_cast<float4*>(o2 + tid * 8 + 4) = t1;
        }
    }
    __syncthreads();

    for (int ch = 0; ch < NCH; ++ch) {
        const int cb = ch & 1;
        if (ch + 1 < NCH) {
            const float* ln = lg + (long)(ch + 1) * 64 * KK;
            r0 = *reinterpret_cast<const float4*>(ln + tid * 8);
            r1 = *reinterpret_cast<const float4*>(ln + tid * 8 + 4);
        }
        const float* xc = xp + (long)ch * 64 * DD;
        const float* pb = &pwl[cb][0];
#pragma unroll 8
        for (int i = 0; i < 64; ++i) {
            const float xv = xc[(long)i * DD];
#pragma unroll
            for (int q = 0; q < 8; ++q) {
                const float4 w = *reinterpret_cast<const float4*>(pb + i * KK + q * 4);
                acc[4*q]   = fmaf(w.x, xv, acc[4*q]);
                acc[4*q+1] = fmaf(w.y, xv, acc[4*q+1]);
                acc[4*q+2] = fmaf(w.z, xv, acc[4*q+2]);
                acc[4*q+3] = fmaf(w.w, xv, acc[4*q+3]);
            }
        }
        if (ch + 1 < NCH) {
            const float4 t0 = make_float4(__expf(r0.x - km[0]) * krv[0],
                                          __expf(r0.y - km[1]) * krv[1],
                                          __expf(r0.z - km[2]) * krv[2],
                                          __expf(r0.w - km[3]) * krv[3]);
            const float4 t1 = make_float4(__expf(r1.x - km[4]) * krv[4],
                                          __expf(r1.y - km[5]) * krv[5],
                                          __expf(r1.z - km[6]) * krv[6],
                                          __expf(r1.w - km[7]) * krv[7]);
            *reinterpret_cast<float4*>(&pwl[cb ^ 1][tid * 8])     = t0;
            *reinterpret_cast<float4*>(&pwl[cb ^ 1][tid * 8 + 4]) = t1;
            if (dc == 0) {
                float* on = o2 + (long)(ch + 1) * 64 * KK;
                *reinterpret_cast<float4*>(on + tid * 8)     = t0;
                *reinterpret_cast<float4*>(on + tid * 8 + 4) = t1;
            }
        }
        __syncthreads();
    }
    float* o = dst + ((long)(sc * BB + b) * KK) * DD + d;
#pragma unroll
    for (int k = 0; k < KK; ++k) o[(long)k * DD] = acc[k];
}

extern "C" void kernel_launch(void* const* d_in, const int* in_sizes, int n_in,
                              void* d_out, int out_size, void* d_ws, size_t ws_size,
                              hipStream_t stream)
{
    const float* x  = (const float*)d_in[0];
    const float* Wp = (const float*)d_in[1];
    const float* bp = (const float*)d_in[2];
    float* out = (float*)d_out;
    float* ws  = (float*)d_ws;

    const size_t wfloats = ws_size / 4;
    const long need = WC2 + 2L * 32768 * KK;   // 12.8 MB total
    const bool mfma_ok = wfloats >= (size_t)need;

    if (mfma_ok) {
        unsigned short* wh = (unsigned short*)(ws + WPKH);
        unsigned short* wl = (unsigned short*)(ws + WPKL);
        unsigned short* fh = (unsigned short*)(ws + PWFH);
        unsigned short* fl = (unsigned short*)(ws + PWFL);
        hipLaunchKernelGGL(k_wprep,       dim3(16),   dim3(256), 0, stream, Wp, wh, wl);
        hipLaunchKernelGGL(k_logits_mfma, dim3(1024), dim3(256), 0, stream, x, wh, wl, ws + WC2);
        hipLaunchKernelGGL(k_comb2,       dim3(128),  dim3(256), 0, stream, ws + WC2, bp, out, ws);
        hipLaunchKernelGGL(k_pwfrag,      dim3(1024), dim3(256), 0, stream, out, ws, fh, fl);
        hipLaunchKernelGGL(k_slots_mfma,  dim3(BB * 16 * 8), dim3(256), 0, stream,
                           x, fh, fl, ws + WC2, 8, SS / 8);
        hipLaunchKernelGGL(k_red,         dim3(256),  dim3(256), 0, stream, ws + WC2, out, 8);
    } else {
        hipLaunchKernelGGL(k_logits4, dim3(512), dim3(256), 0, stream, x, Wp, bp, out);
        hipLaunchKernelGGL(k_smpart,  dim3(128), dim3(256), 0, stream, out, ws);
        hipLaunchKernelGGL(k_smcomb,  dim3(1),   dim3(256), 0, stream, ws);
        int SC = 0;
        if      (wfloats >= (size_t)(WC2 + 8L * 262144)) SC = 8;
        else if (wfloats >= (size_t)(WC2 + 4L * 262144)) SC = 4;
        else if (wfloats >= (size_t)(WC2 + 2L * 262144)) SC = 2;
        else if (wfloats >= (size_t)(WC2 + 1L * 262144)) SC = 1;
        if (SC >= 1) {
            hipLaunchKernelGGL(k_slots2pw, dim3(BB * 4 * SC), dim3(256), 0, stream,
                               x, out, ws, ws + WC2, SC, SS / SC);
            hipLaunchKernelGGL(k_red, dim3(256), dim3(256), 0, stream, ws + WC2, out, SC);
        } else {
            hipLaunchKernelGGL(k_slots2pw, dim3(BB * 4), dim3(256), 0, stream,
                               x, out, ws, out + O3, 1, SS);
            hipLaunchKernelGGL(k_red, dim3(256), dim3(256), 0, stream, out + O3, out, 1);
        }
    }
}